// Round 7
// baseline (1665.074 us; speedup 1.0000x reference)
//
#include <hip/hip_runtime.h>

// BeitSelfAttention — f32 pipeline.
// This round (loc_attn only): merged-chunk QK^T + single-pass softmax.
//  - s[5][13] accumulators in VGPR: Q LDS fragments read ONCE (208 vs 1040
//    ds_read_b128/wave), 5 independent K-row loads in flight per d4.
//  - softmax single-pass over all 320 keys: one max/sum butterfly pair per
//    row (was per row-chunk: 2350 -> ~780 instrs/wave), no online alpha
//    rescale chain (also removes inter-chunk serial dependency).
//  - PV unchanged (per-wave Plds broadcast, 4-key batches).
// Kept from R5: XCD-contiguous block swizzle, arithmetic rel-pos bias index.
// gemm_f32 / cls_attn verbatim.
// Shapes: B=8 S=1569 D=768 NH=12 DH=64 NCLS=1 BS=49 M=32 NKV=6

#define S_TOT   1569
#define NBATCH  8

// -------- gemm_f32: QKV = X(nTok x 768) @ [Wq|Wk|Wv](768 x 2304) + bias
__global__ __launch_bounds__(256) void gemm_f32(const float* __restrict__ hs,
                                                const float* __restrict__ Wq,
                                                const float* __restrict__ Wk,
                                                const float* __restrict__ Wv,
                                                const float* __restrict__ bq,
                                                const float* __restrict__ bv,
                                                float* __restrict__ Q,
                                                float* __restrict__ K,
                                                float* __restrict__ V,
                                                int b0, int nTok) {
    __shared__ float As[128][20];   // [t][k]: 16 k + 4 pad
    __shared__ float Bs[16][136];   // [k][n]: 128 n + 8 pad
    int tid = threadIdx.x;
    int t0 = blockIdx.x * 128;
    int n0 = blockIdx.y * 128;
    int which = n0 / 768;
    int ng0 = n0 - which * 768;
    const float* W = (which == 0) ? Wq : (which == 1 ? Wk : Wv);
    const float* Xb = hs + (size_t)b0 * S_TOT * 768;

    int tr = tid >> 4;              // 0..15: rows tr*8 .. tr*8+7
    int tc = tid & 15;              // cols tc*4..+4 and 64+tc*4..+4

    int sat = tid >> 2;             // 0..63 (+0 / +64 halves)
    int sak = (tid & 3) * 4;        // k-offset 0,4,8,12
    int sbk = tid >> 4;             // 0..15
    int sbn = (tid & 15) * 8;       // 0..120

    float acc[8][8];
#pragma unroll
    for (int i = 0; i < 8; i++)
#pragma unroll
        for (int j = 0; j < 8; j++) acc[i][j] = 0.f;

    for (int k0 = 0; k0 < 768; k0 += 16) {
#pragma unroll
        for (int hh = 0; hh < 2; hh++) {
            int t = t0 + sat + hh * 64;
            float4 xv = make_float4(0.f, 0.f, 0.f, 0.f);
            if (t < nTok)
                xv = *(const float4*)(Xb + (size_t)t * 768 + k0 + sak);
            *(float4*)&As[sat + hh * 64][sak] = xv;
        }
        {
            const float* wr_ = W + (size_t)(k0 + sbk) * 768 + ng0 + sbn;
            *(float4*)&Bs[sbk][sbn]     = *(const float4*)(wr_);
            *(float4*)&Bs[sbk][sbn + 4] = *(const float4*)(wr_ + 4);
        }
        __syncthreads();

#pragma unroll
        for (int kq = 0; kq < 4; kq++) {
            float4 xa[8];
#pragma unroll
            for (int i = 0; i < 8; i++)
                xa[i] = *(const float4*)&As[tr * 8 + i][kq * 4];
#pragma unroll
            for (int kk = 0; kk < 4; kk++) {
                int k = kq * 4 + kk;
                float4 w0 = *(const float4*)&Bs[k][tc * 4];
                float4 w1 = *(const float4*)&Bs[k][64 + tc * 4];
#pragma unroll
                for (int i = 0; i < 8; i++) {
                    float a = (kk == 0) ? xa[i].x : (kk == 1) ? xa[i].y
                            : (kk == 2) ? xa[i].z : xa[i].w;
                    acc[i][0] = fmaf(a, w0.x, acc[i][0]);
                    acc[i][1] = fmaf(a, w0.y, acc[i][1]);
                    acc[i][2] = fmaf(a, w0.z, acc[i][2]);
                    acc[i][3] = fmaf(a, w0.w, acc[i][3]);
                    acc[i][4] = fmaf(a, w1.x, acc[i][4]);
                    acc[i][5] = fmaf(a, w1.y, acc[i][5]);
                    acc[i][6] = fmaf(a, w1.z, acc[i][6]);
                    acc[i][7] = fmaf(a, w1.w, acc[i][7]);
                }
            }
        }
        __syncthreads();
    }

    float* dst = (which == 0) ? Q : (which == 1 ? K : V);
    const float* bias = (which == 0) ? bq : (which == 2 ? bv : nullptr);
#pragma unroll
    for (int hh = 0; hh < 2; hh++) {
        int nn = ng0 + hh * 64 + tc * 4;        // 0..767, multiple of 4
        int h = nn >> 6, d = nn & 63;
        float4 bv4 = make_float4(0.f, 0.f, 0.f, 0.f);
        if (bias) bv4 = *(const float4*)(bias + nn);
#pragma unroll
        for (int i = 0; i < 8; i++) {
            int t = t0 + tr * 8 + i;
            if (t >= nTok) continue;
            int bl = t / S_TOT;
            int s = t - bl * S_TOT;
            float4 o;
            o.x = acc[i][hh * 4 + 0] + bv4.x;
            o.y = acc[i][hh * 4 + 1] + bv4.y;
            o.z = acc[i][hh * 4 + 2] + bv4.z;
            o.w = acc[i][hh * 4 + 3] + bv4.w;
            *(float4*)(dst + ((size_t)(bl * 12 + h) * S_TOT + s) * 64 + d) = o;
        }
    }
}

// -------- cls attention (unchanged)
__global__ __launch_bounds__(256) void cls_attn(const float* __restrict__ Q,
                                                const float* __restrict__ K,
                                                const float* __restrict__ V,
                                                const float* __restrict__ rel,
                                                const int* __restrict__ rpi,
                                                float* __restrict__ out, int b0) {
    int bh = blockIdx.x;
    int bl = bh / 12, h = bh - bl * 12;
    __shared__ float p[S_TOT];
    __shared__ float4 qs4[16];
    __shared__ float red[256];
    __shared__ float wred[8];
    int tid = threadIdx.x, lane = tid & 63, w = tid >> 6;
    size_t base = (size_t)bh * S_TOT * 64;
    const float* Qb = Q + base;
    const float* Kb = K + base;
    const float* Vb = V + base;
    if (tid < 64) ((float*)qs4)[tid] = Qb[tid];
    __syncthreads();

    float lmx = -1e30f;
    for (int j = tid; j < S_TOT; j += 256) {
        const float4* kr = (const float4*)(Kb + j * 64);
        float a = 0.f;
#pragma unroll
        for (int d4 = 0; d4 < 16; d4++) {
            float4 kv = kr[d4];
            float4 qv = qs4[d4];
            a = fmaf(qv.x, kv.x, a); a = fmaf(qv.y, kv.y, a);
            a = fmaf(qv.z, kv.z, a); a = fmaf(qv.w, kv.w, a);
        }
        a = a * 0.125f + rel[rpi[j] * 12 + h];
        p[j] = a;
        lmx = fmaxf(lmx, a);
    }
#pragma unroll
    for (int off = 32; off > 0; off >>= 1) lmx = fmaxf(lmx, __shfl_xor(lmx, off));
    if (lane == 0) wred[w] = lmx;
    __syncthreads();
    float mx = fmaxf(fmaxf(wred[0], wred[1]), fmaxf(wred[2], wred[3]));
    float lsum = 0.f;
    for (int j = tid; j < S_TOT; j += 256) {
        float e = __expf(p[j] - mx);
        p[j] = e;
        lsum += e;
    }
#pragma unroll
    for (int off = 32; off > 0; off >>= 1) lsum += __shfl_xor(lsum, off);
    if (lane == 0) wred[4 + w] = lsum;
    __syncthreads();
    float inv = 1.0f / (wred[4] + wred[5] + wred[6] + wred[7]);
    float acc = 0.f;
    for (int j = w; j < S_TOT; j += 4) acc = fmaf(p[j], Vb[j * 64 + lane], acc);
    red[w * 64 + lane] = acc;
    __syncthreads();
    if (w == 0) {
        float o = (red[lane] + red[64 + lane] + red[128 + lane] + red[192 + lane]) * inv;
        out[(size_t)(b0 + bl) * S_TOT * 768 + h * 64 + lane] = o;
    }
}

// -------- block-sparse local attention — merged-chunk QK^T, single-pass
// softmax, XCD-swizzled, arithmetic rel-pos bias index.
__global__ __launch_bounds__(256, 4) void loc_attn(const float* __restrict__ Q,
                                                   const float* __restrict__ K,
                                                   const float* __restrict__ V,
                                                   const float* __restrict__ rel,
                                                   const int* __restrict__ rand_idx,
                                                   float* __restrict__ out,
                                                   int b0, int ng) {
    // ---- XCD-contiguous decode (total = 32*ng divisible by 8, ng=12*cb)
    int d = blockIdx.x;
    int xcd = d & 7, kk_ = d >> 3;
    int slot = xcd * (ng << 2) + kk_;      // ng*4 = total/8 blocks per XCD
    int g = slot >> 5;                      // group = h + 12*bl
    int m = slot & 31;
    int h = g % 12;
    int bl = g / 12;

    __shared__ float Qlds[52][64];      // rows 49..51 zero-filled
    __shared__ float Plds[4][13][64];   // per-wave P chunk transpose buffer
    __shared__ int   tok[320];          // 295 real + padding (token 0)
    int tid = threadIdx.x, lane = tid & 63, w = tid >> 6;

    size_t base = (size_t)((bl * 12 + h) * S_TOT) * 64;
    const float* Qb = Q + base;
    const float* Kb = K + base;
    const float* Vb = V + base;

    // stage token table (295 entries, pad to 320 with token 0)
    for (int jj = tid; jj < 320; jj += 256) {
        int t = 0;
        if (jj >= 1 && jj < 295) {
            int j1 = jj - 1;
            int n = j1 / 49;
            int q = j1 - n * 49;
            int a;
            if (n == 0)      a = (m + 31) & 31;
            else if (n == 1) a = m;
            else if (n == 2) a = (m + 1) & 31;
            else             a = rand_idx[m * 3 + (n - 3)];
            t = 1 + a * 49 + q;
        }
        tok[jj] = t;
    }
    // stage Q tile (49 rows + 3 zero rows), coalesced
    for (int idx = tid; idx < 52 * 64; idx += 256) {
        int r = idx >> 6, c = idx & 63;
        float qv = 0.f;
        if (r < 49) qv = Qb[(size_t)(1 + m * 49 + r) * 64 + c];
        ((float*)Qlds)[idx] = qv;
    }
    __syncthreads();

    // ---- per-row packed query coords cq[r] = zq*729 + yq*27 + xq
    int cq[13];
#pragma unroll
    for (int r = 0; r < 13; r++) {
        int i = w + 4 * r;
        int qr = 1 + m * 49 + i;
        if (qr > S_TOT - 1) qr = S_TOT - 1;   // clamp for pad rows 49..51
        int pq = qr - 1;
        int zq = pq / 196;
        int rem = pq - zq * 196;
        int yq = rem / 14;
        int xq = rem - yq * 14;
        cq[r] = zq * 729 + yq * 27 + xq;
    }

    // ---- per-chunk (key = c*64+lane) constants
    const float* kp_[5];
    int cj_[5];
    bool cls_[5], jv_[5];
#pragma unroll
    for (int c = 0; c < 5; c++) {
        int j = c * 64 + lane;
        int t = tok[j];
        kp_[c] = Kb + (size_t)t * 64;
        int pj = t - 1;
        int zj = pj / 196;
        int remj = pj - zj * 196;
        int yj = remj / 14;
        int xj = remj - yj * 14;
        cj_[c] = zj * 729 + yj * 27 + xj;
        cls_[c] = (t == 0);
        jv_[c] = (j < 295);
    }

    // ---- merged QK^T: s[c][r] = Q[row r]·K[key c], all 5 chunks at once
    float s[5][13];
#pragma unroll
    for (int c = 0; c < 5; c++)
#pragma unroll
        for (int r = 0; r < 13; r++) s[c][r] = 0.f;

#pragma unroll 4
    for (int d4 = 0; d4 < 16; d4++) {
        float4 kv0 = *(const float4*)(kp_[0] + d4 * 4);
        float4 kv1 = *(const float4*)(kp_[1] + d4 * 4);
        float4 kv2 = *(const float4*)(kp_[2] + d4 * 4);
        float4 kv3 = *(const float4*)(kp_[3] + d4 * 4);
        float4 kv4 = *(const float4*)(kp_[4] + d4 * 4);
#pragma unroll
        for (int r = 0; r < 13; r++) {
            float4 qv = *(const float4*)&Qlds[w + 4 * r][d4 * 4];   // broadcast
            s[0][r] = fmaf(qv.x, kv0.x, s[0][r]); s[0][r] = fmaf(qv.y, kv0.y, s[0][r]);
            s[0][r] = fmaf(qv.z, kv0.z, s[0][r]); s[0][r] = fmaf(qv.w, kv0.w, s[0][r]);
            s[1][r] = fmaf(qv.x, kv1.x, s[1][r]); s[1][r] = fmaf(qv.y, kv1.y, s[1][r]);
            s[1][r] = fmaf(qv.z, kv1.z, s[1][r]); s[1][r] = fmaf(qv.w, kv1.w, s[1][r]);
            s[2][r] = fmaf(qv.x, kv2.x, s[2][r]); s[2][r] = fmaf(qv.y, kv2.y, s[2][r]);
            s[2][r] = fmaf(qv.z, kv2.z, s[2][r]); s[2][r] = fmaf(qv.w, kv2.w, s[2][r]);
            s[3][r] = fmaf(qv.x, kv3.x, s[3][r]); s[3][r] = fmaf(qv.y, kv3.y, s[3][r]);
            s[3][r] = fmaf(qv.z, kv3.z, s[3][r]); s[3][r] = fmaf(qv.w, kv3.w, s[3][r]);
            s[4][r] = fmaf(qv.x, kv4.x, s[4][r]); s[4][r] = fmaf(qv.y, kv4.y, s[4][r]);
            s[4][r] = fmaf(qv.z, kv4.z, s[4][r]); s[4][r] = fmaf(qv.w, kv4.w, s[4][r]);
        }
    }

    // ---- single-pass softmax per row (bias + one max/sum butterfly pair)
    float fl[13];
#pragma unroll
    for (int r = 0; r < 13; r++) {
        float sv0, sv1, sv2, sv3, sv4;
        {
            int b0i = cls_[0] ? 10936 : (cq[r] - cj_[0] + 5467);
            int b1i = cls_[1] ? 10936 : (cq[r] - cj_[1] + 5467);
            int b2i = cls_[2] ? 10936 : (cq[r] - cj_[2] + 5467);
            int b3i = cls_[3] ? 10936 : (cq[r] - cj_[3] + 5467);
            int b4i = cls_[4] ? 10936 : (cq[r] - cj_[4] + 5467);
            sv0 = fmaf(s[0][r], 0.125f, rel[b0i * 12 + h]);   // chunks 0..3 always valid
            sv1 = fmaf(s[1][r], 0.125f, rel[b1i * 12 + h]);
            sv2 = fmaf(s[2][r], 0.125f, rel[b2i * 12 + h]);
            sv3 = fmaf(s[3][r], 0.125f, rel[b3i * 12 + h]);
            sv4 = jv_[4] ? fmaf(s[4][r], 0.125f, rel[b4i * 12 + h]) : -1e30f;
        }
        float mx = fmaxf(fmaxf(fmaxf(sv0, sv1), fmaxf(sv2, sv3)), sv4);
#pragma unroll
        for (int off = 32; off > 0; off >>= 1) mx = fmaxf(mx, __shfl_xor(mx, off));
        float e0 = __expf(sv0 - mx);
        float e1 = __expf(sv1 - mx);
        float e2 = __expf(sv2 - mx);
        float e3 = __expf(sv3 - mx);
        float e4 = __expf(sv4 - mx);
        s[0][r] = e0; s[1][r] = e1; s[2][r] = e2; s[3][r] = e3; s[4][r] = e4;
        float sum = ((e0 + e1) + (e2 + e3)) + e4;
#pragma unroll
        for (int off = 32; off > 0; off >>= 1) sum += __shfl_xor(sum, off);
        fl[r] = sum;
    }

    // ---- PV: per chunk, write P to per-wave Plds, 4-key-batched fma
    float facc[13];
#pragma unroll
    for (int r = 0; r < 13; r++) facc[r] = 0.f;

#pragma unroll
    for (int c = 0; c < 5; c++) {
#pragma unroll
        for (int r = 0; r < 13; r++) Plds[w][r][lane] = s[c][r];
#pragma unroll 4
        for (int jg = 0; jg < 16; jg++) {
            int jb = c * 64 + jg * 4;
            int t0 = tok[jb + 0], t1 = tok[jb + 1], t2 = tok[jb + 2], t3 = tok[jb + 3];
            float v0 = Vb[(size_t)t0 * 64 + lane];
            float v1 = Vb[(size_t)t1 * 64 + lane];
            float v2 = Vb[(size_t)t2 * 64 + lane];
            float v3 = Vb[(size_t)t3 * 64 + lane];
#pragma unroll
            for (int r = 0; r < 13; r++) {
                float4 p4 = *(const float4*)&Plds[w][r][jg * 4];        // broadcast
                facc[r] = fmaf(p4.x, v0, facc[r]);
                facc[r] = fmaf(p4.y, v1, facc[r]);
                facc[r] = fmaf(p4.z, v2, facc[r]);
                facc[r] = fmaf(p4.w, v3, facc[r]);
            }
        }
    }

    // ---- epilogue: normalize and store valid rows
    int nrows = (w == 0) ? 13 : 12;
    for (int r = 0; r < nrows; r++) {
        int i = w + 4 * r;
        int st = 1 + m * 49 + i;
        out[((size_t)(b0 + bl) * S_TOT + st) * 768 + h * 64 + lane] = facc[r] / fl[r];
    }
}

extern "C" void kernel_launch(void* const* d_in, const int* in_sizes, int n_in,
                              void* d_out, int out_size, void* d_ws, size_t ws_size,
                              hipStream_t stream) {
    (void)in_sizes; (void)n_in; (void)out_size;
    const float* hs  = (const float*)d_in[0];
    const float* Wq  = (const float*)d_in[1];
    const float* bq  = (const float*)d_in[2];
    const float* Wk  = (const float*)d_in[3];
    const float* Wv  = (const float*)d_in[4];
    const float* bv  = (const float*)d_in[5];
    const float* rel = (const float*)d_in[6];
    const int*   rpi = (const int*)d_in[7];
    const int*   rnd = (const int*)d_in[8];
    float* out = (float*)d_out;
    char* ws = (char*)d_ws;

    // ws layout: Q | K | V  (each C * PBUF bytes)
    constexpr size_t PBUF = (size_t)12 * S_TOT * 64 * 4;     // 4,819,968 per batch

    int C = 1;
    if (ws_size >= 3 * PBUF) {
        size_t c = ws_size / (3 * PBUF);
        C = (c >= NBATCH) ? NBATCH : (int)c;
        if (C < 1) C = 1;
    }
    float* Q = (float*)(ws);
    float* K = (float*)(ws + (size_t)C * PBUF);
    float* V = (float*)(ws + (size_t)C * PBUF * 2);

    for (int b0 = 0; b0 < NBATCH; b0 += C) {
        int cb = (NBATCH - b0 < C) ? (NBATCH - b0) : C;
        int nTok = cb * S_TOT;
        gemm_f32<<<dim3((nTok + 127) / 128, 18), dim3(256), 0, stream>>>(
            hs, Wq, Wk, Wv, bq, bv, Q, K, V, b0, nTok);
        cls_attn<<<dim3(12 * cb), dim3(256), 0, stream>>>(Q, K, V, rel, rpi, out, b0);
        int ngrp = 12 * cb;
        loc_attn<<<dim3(32 * ngrp), dim3(256), 0, stream>>>(
            Q, K, V, rel, rnd, out, b0, ngrp);
    }
}

// Round 8
// 1198.739 us; speedup vs baseline: 1.3890x; 1.3890x over previous
//
#include <hip/hip_runtime.h>

// BeitSelfAttention — f32 pipeline.
// R7 post-mortem: merged-chunk loc_attn spilled s[5][13] to scratch
// (WRITE_SIZE 200MB->2.17GB, VALUBusy 26%) — REVERTED to the R6-measured
// 550us loc_attn (per-chunk flash loop, XCD swizzle, arithmetic bias index).
// This round's forward change is gemm_f32 only:
//  - As-read 4-way LDS bank conflict fix: XOR col-group swizzle keyed on
//    (row>>3)&3 (rows 8 apart land on same banks at any float4 pitch;
//    swizzle spreads the wave's 4 rows across 4 distinct 16B slots).
//  - branchless A staging: t clamped to nTok-1 (garbage rows' acc entries
//    are never stored), removes per-row guard + zero-fill.
// cls_attn verbatim.
// Shapes: B=8 S=1569 D=768 NH=12 DH=64 NCLS=1 BS=49 M=32 NKV=6

#define S_TOT   1569
#define NBATCH  8

// -------- gemm_f32: QKV = X(nTok x 768) @ [Wq|Wk|Wv](768 x 2304) + bias
__global__ __launch_bounds__(256) void gemm_f32(const float* __restrict__ hs,
                                                const float* __restrict__ Wq,
                                                const float* __restrict__ Wk,
                                                const float* __restrict__ Wv,
                                                const float* __restrict__ bq,
                                                const float* __restrict__ bv,
                                                float* __restrict__ Q,
                                                float* __restrict__ K,
                                                float* __restrict__ V,
                                                int b0, int nTok) {
    __shared__ float As[128][20];   // [t][swizzled k]: 16 k + 4 pad
    __shared__ float Bs[16][136];   // [k][n]: 128 n + 8 pad
    int tid = threadIdx.x;
    int t0 = blockIdx.x * 128;
    int n0 = blockIdx.y * 128;
    int which = n0 / 768;
    int ng0 = n0 - which * 768;
    const float* W = (which == 0) ? Wq : (which == 1 ? Wk : Wv);
    const float* Xb = hs + (size_t)b0 * S_TOT * 768;

    int tr = tid >> 4;              // 0..15: rows tr*8 .. tr*8+7
    int tc = tid & 15;              // cols tc*4..+4 and 64+tc*4..+4

    int sat = tid >> 2;             // 0..63 (+0 / +64 halves)
    int sac = tid & 3;              // k col-group 0..3
    int sbk = tid >> 4;             // 0..15
    int sbn = (tid & 15) * 8;       // 0..120

    // swizzled store col-group: c ^ ((t>>3)&3)  (same for both t-halves,
    // since +64 rows shifts t>>3 by 8 ≡ 0 mod 4)
    int scg = (sac ^ ((sat >> 3) & 3)) * 4;
    int rswz = (tr & 3);            // read-side swizzle key = (row>>3)&3

    float acc[8][8];
#pragma unroll
    for (int i = 0; i < 8; i++)
#pragma unroll
        for (int j = 0; j < 8; j++) acc[i][j] = 0.f;

    for (int k0 = 0; k0 < 768; k0 += 16) {
        // ---- stage A (branchless: clamp row; invalid rows never stored)
#pragma unroll
        for (int hh = 0; hh < 2; hh++) {
            int t = t0 + sat + hh * 64;
            if (t >= nTok) t = nTok - 1;
            float4 xv = *(const float4*)(Xb + (size_t)t * 768 + k0 + sac * 4);
            *(float4*)&As[sat + hh * 64][scg] = xv;
        }
        // ---- stage B
        {
            const float* wr_ = W + (size_t)(k0 + sbk) * 768 + ng0 + sbn;
            *(float4*)&Bs[sbk][sbn]     = *(const float4*)(wr_);
            *(float4*)&Bs[sbk][sbn + 4] = *(const float4*)(wr_ + 4);
        }
        __syncthreads();

#pragma unroll
        for (int kq = 0; kq < 4; kq++) {
            float4 xa[8];
            int rc = (kq ^ rswz) * 4;           // swizzled read col-group
#pragma unroll
            for (int i = 0; i < 8; i++)
                xa[i] = *(const float4*)&As[tr * 8 + i][rc];
#pragma unroll
            for (int kk = 0; kk < 4; kk++) {
                int k = kq * 4 + kk;
                float4 w0 = *(const float4*)&Bs[k][tc * 4];
                float4 w1 = *(const float4*)&Bs[k][64 + tc * 4];
#pragma unroll
                for (int i = 0; i < 8; i++) {
                    float a = (kk == 0) ? xa[i].x : (kk == 1) ? xa[i].y
                            : (kk == 2) ? xa[i].z : xa[i].w;
                    acc[i][0] = fmaf(a, w0.x, acc[i][0]);
                    acc[i][1] = fmaf(a, w0.y, acc[i][1]);
                    acc[i][2] = fmaf(a, w0.z, acc[i][2]);
                    acc[i][3] = fmaf(a, w0.w, acc[i][3]);
                    acc[i][4] = fmaf(a, w1.x, acc[i][4]);
                    acc[i][5] = fmaf(a, w1.y, acc[i][5]);
                    acc[i][6] = fmaf(a, w1.z, acc[i][6]);
                    acc[i][7] = fmaf(a, w1.w, acc[i][7]);
                }
            }
        }
        __syncthreads();
    }

    float* dst = (which == 0) ? Q : (which == 1 ? K : V);
    const float* bias = (which == 0) ? bq : (which == 2 ? bv : nullptr);
#pragma unroll
    for (int hh = 0; hh < 2; hh++) {
        int nn = ng0 + hh * 64 + tc * 4;        // 0..767, multiple of 4
        int h = nn >> 6, d = nn & 63;
        float4 bv4 = make_float4(0.f, 0.f, 0.f, 0.f);
        if (bias) bv4 = *(const float4*)(bias + nn);
#pragma unroll
        for (int i = 0; i < 8; i++) {
            int t = t0 + tr * 8 + i;
            if (t >= nTok) continue;
            int bl = t / S_TOT;
            int s = t - bl * S_TOT;
            float4 o;
            o.x = acc[i][hh * 4 + 0] + bv4.x;
            o.y = acc[i][hh * 4 + 1] + bv4.y;
            o.z = acc[i][hh * 4 + 2] + bv4.z;
            o.w = acc[i][hh * 4 + 3] + bv4.w;
            *(float4*)(dst + ((size_t)(bl * 12 + h) * S_TOT + s) * 64 + d) = o;
        }
    }
}

// -------- cls attention (unchanged)
__global__ __launch_bounds__(256) void cls_attn(const float* __restrict__ Q,
                                                const float* __restrict__ K,
                                                const float* __restrict__ V,
                                                const float* __restrict__ rel,
                                                const int* __restrict__ rpi,
                                                float* __restrict__ out, int b0) {
    int bh = blockIdx.x;
    int bl = bh / 12, h = bh - bl * 12;
    __shared__ float p[S_TOT];
    __shared__ float4 qs4[16];
    __shared__ float red[256];
    __shared__ float wred[8];
    int tid = threadIdx.x, lane = tid & 63, w = tid >> 6;
    size_t base = (size_t)bh * S_TOT * 64;
    const float* Qb = Q + base;
    const float* Kb = K + base;
    const float* Vb = V + base;
    if (tid < 64) ((float*)qs4)[tid] = Qb[tid];
    __syncthreads();

    float lmx = -1e30f;
    for (int j = tid; j < S_TOT; j += 256) {
        const float4* kr = (const float4*)(Kb + j * 64);
        float a = 0.f;
#pragma unroll
        for (int d4 = 0; d4 < 16; d4++) {
            float4 kv = kr[d4];
            float4 qv = qs4[d4];
            a = fmaf(qv.x, kv.x, a); a = fmaf(qv.y, kv.y, a);
            a = fmaf(qv.z, kv.z, a); a = fmaf(qv.w, kv.w, a);
        }
        a = a * 0.125f + rel[rpi[j] * 12 + h];
        p[j] = a;
        lmx = fmaxf(lmx, a);
    }
#pragma unroll
    for (int off = 32; off > 0; off >>= 1) lmx = fmaxf(lmx, __shfl_xor(lmx, off));
    if (lane == 0) wred[w] = lmx;
    __syncthreads();
    float mx = fmaxf(fmaxf(wred[0], wred[1]), fmaxf(wred[2], wred[3]));
    float lsum = 0.f;
    for (int j = tid; j < S_TOT; j += 256) {
        float e = __expf(p[j] - mx);
        p[j] = e;
        lsum += e;
    }
#pragma unroll
    for (int off = 32; off > 0; off >>= 1) lsum += __shfl_xor(lsum, off);
    if (lane == 0) wred[4 + w] = lsum;
    __syncthreads();
    float inv = 1.0f / (wred[4] + wred[5] + wred[6] + wred[7]);
    float acc = 0.f;
    for (int j = w; j < S_TOT; j += 4) acc = fmaf(p[j], Vb[j * 64 + lane], acc);
    red[w * 64 + lane] = acc;
    __syncthreads();
    if (w == 0) {
        float o = (red[lane] + red[64 + lane] + red[128 + lane] + red[192 + lane]) * inv;
        out[(size_t)(b0 + bl) * S_TOT * 768 + h * 64 + lane] = o;
    }
}

// -------- block-sparse local attention — flash-style, XCD-swizzled,
// arithmetic rel-pos bias index (R6-measured 550us version, verbatim).
__global__ __launch_bounds__(256, 4) void loc_attn(const float* __restrict__ Q,
                                                   const float* __restrict__ K,
                                                   const float* __restrict__ V,
                                                   const float* __restrict__ rel,
                                                   const int* __restrict__ rand_idx,
                                                   float* __restrict__ out,
                                                   int b0, int ng) {
    // ---- XCD-contiguous decode (total = 32*ng divisible by 8, ng=12*cb)
    int d = blockIdx.x;
    int xcd = d & 7, kk_ = d >> 3;
    int slot = xcd * (ng << 2) + kk_;      // ng*4 = total/8 blocks per XCD
    int g = slot >> 5;                      // group = h + 12*bl
    int m = slot & 31;
    int h = g % 12;
    int bl = g / 12;

    __shared__ float Qlds[52][64];      // rows 49..51 zero-filled
    __shared__ float Plds[4][13][64];   // per-wave P chunk transpose buffer
    __shared__ int   tok[320];          // 295 real + padding (token 0)
    int tid = threadIdx.x, lane = tid & 63, w = tid >> 6;

    size_t base = (size_t)((bl * 12 + h) * S_TOT) * 64;
    const float* Qb = Q + base;
    const float* Kb = K + base;
    const float* Vb = V + base;

    // stage token table (295 entries, pad to 320 with token 0)
    for (int jj = tid; jj < 320; jj += 256) {
        int t = 0;
        if (jj >= 1 && jj < 295) {
            int j1 = jj - 1;
            int n = j1 / 49;
            int q = j1 - n * 49;
            int a;
            if (n == 0)      a = (m + 31) & 31;
            else if (n == 1) a = m;
            else if (n == 2) a = (m + 1) & 31;
            else             a = rand_idx[m * 3 + (n - 3)];
            t = 1 + a * 49 + q;
        }
        tok[jj] = t;
    }
    // stage Q tile (49 rows + 3 zero rows), coalesced
    for (int idx = tid; idx < 52 * 64; idx += 256) {
        int r = idx >> 6, c = idx & 63;
        float qv = 0.f;
        if (r < 49) qv = Qb[(size_t)(1 + m * 49 + r) * 64 + c];
        ((float*)Qlds)[idx] = qv;
    }
    __syncthreads();

    // ---- per-row packed query coords cq[r] = zq*729 + yq*27 + xq
    int cq[13];
#pragma unroll
    for (int r = 0; r < 13; r++) {
        int i = w + 4 * r;
        int qr = 1 + m * 49 + i;
        if (qr > S_TOT - 1) qr = S_TOT - 1;   // clamp for pad rows 49..51
        int pq = qr - 1;
        int zq = pq / 196;
        int rem = pq - zq * 196;
        int yq = rem / 14;
        int xq = rem - yq * 14;
        cq[r] = zq * 729 + yq * 27 + xq;
    }

    float fm[13], fl[13], facc[13];
#pragma unroll
    for (int r = 0; r < 13; r++) { fm[r] = -1e30f; fl[r] = 0.f; facc[r] = 0.f; }

    for (int jc = 0; jc < 5; jc++) {
        int j = jc * 64 + lane;
        int tj = tok[j];
        const float* kp = Kb + (size_t)tj * 64;

        // per-lane packed key coords cj (tj==0 -> cls column, bidx=10936)
        int pj = tj - 1;
        int zj = pj / 196;
        int remj = pj - zj * 196;
        int yj = remj / 14;
        int xj = remj - yj * 14;
        int cj = zj * 729 + yj * 27 + xj;
        bool iscls = (tj == 0);

        // ---- QK^T for this 64-key chunk: s[r] = Q[i]·K[tj]
        float s[13];
#pragma unroll
        for (int r = 0; r < 13; r++) s[r] = 0.f;
#pragma unroll 4
        for (int d4 = 0; d4 < 16; d4++) {
            float4 kv = *(const float4*)(kp + d4 * 4);
#pragma unroll
            for (int r = 0; r < 13; r++) {
                float4 qv = *(const float4*)&Qlds[w + 4 * r][d4 * 4];   // broadcast
                s[r] = fmaf(qv.x, kv.x, s[r]);
                s[r] = fmaf(qv.y, kv.y, s[r]);
                s[r] = fmaf(qv.z, kv.z, s[r]);
                s[r] = fmaf(qv.w, kv.w, s[r]);
            }
        }

        // ---- bias + online softmax (per-row butterflies), write P chunk
        bool jv = j < 295;
#pragma unroll
        for (int r = 0; r < 13; r++) {
            // bidx = (dz+7)*729 + (dy+13)*27 + (dx+13) = cq - cj + 5467
            int bidx = iscls ? 10936 : (cq[r] - cj + 5467);
            float sv = jv ? fmaf(s[r], 0.125f, rel[bidx * 12 + h])
                          : -1e30f;
            float mx = sv;
#pragma unroll
            for (int off = 32; off > 0; off >>= 1) mx = fmaxf(mx, __shfl_xor(mx, off));
            float mnew = fmaxf(fm[r], mx);
            float p = __expf(sv - mnew);
            float alpha = __expf(fm[r] - mnew);
            fm[r] = mnew;
            float ps = p;
#pragma unroll
            for (int off = 32; off > 0; off >>= 1) ps += __shfl_xor(ps, off);
            fl[r] = fmaf(fl[r], alpha, ps);
            facc[r] *= alpha;
            Plds[w][r][lane] = p;
        }

        // ---- PV for this chunk: 4 keys per step, P via b128 broadcast
#pragma unroll 4
        for (int jg = 0; jg < 16; jg++) {
            int jb = jc * 64 + jg * 4;
            int t0 = tok[jb + 0], t1 = tok[jb + 1], t2 = tok[jb + 2], t3 = tok[jb + 3];
            float v0 = Vb[(size_t)t0 * 64 + lane];
            float v1 = Vb[(size_t)t1 * 64 + lane];
            float v2 = Vb[(size_t)t2 * 64 + lane];
            float v3 = Vb[(size_t)t3 * 64 + lane];
#pragma unroll
            for (int r = 0; r < 13; r++) {
                float4 p4 = *(const float4*)&Plds[w][r][jg * 4];        // broadcast
                facc[r] = fmaf(p4.x, v0, facc[r]);
                facc[r] = fmaf(p4.y, v1, facc[r]);
                facc[r] = fmaf(p4.z, v2, facc[r]);
                facc[r] = fmaf(p4.w, v3, facc[r]);
            }
        }
    }

    // ---- epilogue: normalize and store valid rows
    int nrows = (w == 0) ? 13 : 12;
    for (int r = 0; r < nrows; r++) {
        int i = w + 4 * r;
        int st = 1 + m * 49 + i;
        out[((size_t)(b0 + bl) * S_TOT + st) * 768 + h * 64 + lane] = facc[r] / fl[r];
    }
}

extern "C" void kernel_launch(void* const* d_in, const int* in_sizes, int n_in,
                              void* d_out, int out_size, void* d_ws, size_t ws_size,
                              hipStream_t stream) {
    (void)in_sizes; (void)n_in; (void)out_size;
    const float* hs  = (const float*)d_in[0];
    const float* Wq  = (const float*)d_in[1];
    const float* bq  = (const float*)d_in[2];
    const float* Wk  = (const float*)d_in[3];
    const float* Wv  = (const float*)d_in[4];
    const float* bv  = (const float*)d_in[5];
    const float* rel = (const float*)d_in[6];
    const int*   rpi = (const int*)d_in[7];
    const int*   rnd = (const int*)d_in[8];
    float* out = (float*)d_out;
    char* ws = (char*)d_ws;

    // ws layout: Q | K | V  (each C * PBUF bytes)
    constexpr size_t PBUF = (size_t)12 * S_TOT * 64 * 4;     // 4,819,968 per batch

    int C = 1;
    if (ws_size >= 3 * PBUF) {
        size_t c = ws_size / (3 * PBUF);
        C = (c >= NBATCH) ? NBATCH : (int)c;
        if (C < 1) C = 1;
    }
    float* Q = (float*)(ws);
    float* K = (float*)(ws + (size_t)C * PBUF);
    float* V = (float*)(ws + (size_t)C * PBUF * 2);

    for (int b0 = 0; b0 < NBATCH; b0 += C) {
        int cb = (NBATCH - b0 < C) ? (NBATCH - b0) : C;
        int nTok = cb * S_TOT;
        gemm_f32<<<dim3((nTok + 127) / 128, 18), dim3(256), 0, stream>>>(
            hs, Wq, Wk, Wv, bq, bv, Q, K, V, b0, nTok);
        cls_attn<<<dim3(12 * cb), dim3(256), 0, stream>>>(Q, K, V, rel, rpi, out, b0);
        int ngrp = 12 * cb;
        loc_attn<<<dim3(32 * ngrp), dim3(256), 0, stream>>>(
            Q, K, V, rel, rnd, out, b0, ngrp);
    }
}